// Round 12
// baseline (1016.337 us; speedup 1.0000x reference)
//
#include <hip/hip_runtime.h>
#include <hip/hip_bf16.h>
#include <stdint.h>

#define D_EMB 128
#define D_NLP 768
#define BM 64
#define BK 64
#define NKC (D_NLP / BK)   // 12 k-chunks
#define NREP 6             // diagnostic repeat factor (visibility > 180us fills)

typedef __attribute__((ext_vector_type(8))) short bf16x8;
typedef __attribute__((ext_vector_type(4))) float f32x4;
typedef __attribute__((ext_vector_type(8))) unsigned short u16x8;

__device__ __forceinline__ unsigned short f2bf(float f) {
  unsigned u = __builtin_bit_cast(unsigned, f);
  u += 0x7fffu + ((u >> 16) & 1u);   // RTNE (NaN-free inputs)
  return (unsigned short)(u >> 16);
}

__device__ __forceinline__ bf16x8 pack8(const float4& a, const float4& b) {
  u16x8 v;
  v[0] = __builtin_bit_cast(unsigned short, __float2bfloat16(a.x));
  v[1] = __builtin_bit_cast(unsigned short, __float2bfloat16(a.y));
  v[2] = __builtin_bit_cast(unsigned short, __float2bfloat16(a.z));
  v[3] = __builtin_bit_cast(unsigned short, __float2bfloat16(a.w));
  v[4] = __builtin_bit_cast(unsigned short, __float2bfloat16(b.x));
  v[5] = __builtin_bit_cast(unsigned short, __float2bfloat16(b.y));
  v[6] = __builtin_bit_cast(unsigned short, __float2bfloat16(b.z));
  v[7] = __builtin_bit_cast(unsigned short, __float2bfloat16(b.w));
  return __builtin_bit_cast(bf16x8, v);
}

__device__ __forceinline__ void sink4(float4 v) {
  asm volatile("" :: "v"(v.x), "v"(v.y), "v"(v.z), "v"(v.w));
}
__device__ __forceinline__ void sinku4(uint4 v) {
  asm volatile("" :: "v"(v.x), "v"(v.y), "v"(v.z), "v"(v.w));
}

// ---- kernel W: w0 (128x768 f32) -> bf16, pre-swizzled per 64-k chunk (B path).
__global__ void kw(const float* __restrict__ w0, unsigned short* __restrict__ w0s,
                   int* __restrict__ mn) {
  if (blockIdx.x == 0 && threadIdx.x == 0) mn[0] = 0x7fffffff;
  int t = blockIdx.x * 256 + threadIdx.x;       // 12288 units
  if (t >= (D_EMB * D_NLP) / 8) return;
  int u = t & 7, row = (t >> 3) & 127, kc = t >> 10;
  const float4* src = (const float4*)(w0 + (size_t)row * D_NLP + kc * 64 + ((u ^ (row & 7)) * 8));
  float4 v0 = src[0], v1 = src[1];
  u16x8 o;
  o[0] = f2bf(v0.x); o[1] = f2bf(v0.y); o[2] = f2bf(v0.z); o[3] = f2bf(v0.w);
  o[4] = f2bf(v1.x); o[5] = f2bf(v1.y); o[6] = f2bf(v1.z); o[7] = f2bf(v1.w);
  *(u16x8*)(w0s + (size_t)t * 8) = o;
}

// ---- kernel M: mn = min_e max(ei[0][e], ei[1][e])
__global__ void km(const int* __restrict__ ei, int E, int* __restrict__ mn) {
  int t = blockIdx.x * blockDim.x + threadIdx.x;
  int stride = gridDim.x * blockDim.x;
  int m = 0x7fffffff;
  for (int e = t; e < E; e += stride) {
    int a = ei[e], b = ei[E + e];
    int q = a > b ? a : b;
    m = q < m ? q : m;
  }
  #pragma unroll
  for (int off = 32; off; off >>= 1) {
    int o = __shfl_xor(m, off);
    m = o < m ? o : m;
  }
  if ((threadIdx.x & 63) == 0) atomicMin(mn, m);
}

// ======================= DIAGNOSTIC ABLATION =======================
// Same pipeline structure as kc, x6 permuted row-tile passes so each dispatch
// is > the ~180us harness fills and shows its own counters.
// MODE 0: staging skeleton only. MODE 1: + ds_reads (sunk). MODE 2: full.
template <int MODE>
__global__ __launch_bounds__(256) void kdiag(
    const float* __restrict__ z0, const unsigned short* __restrict__ w0s,
    float* __restrict__ dummy, int N, int nblk) {
  extern __shared__ char smem[];
  float* Al = (float*)smem;                              // 3 x 64 x 64f = 48KB
  unsigned short* Bl = (unsigned short*)(smem + 49152);  // 2 x 8192 = 32KB

  const int tid = threadIdx.x;
  const int lane = tid & 63;
  const int wave = tid >> 6;
  const int kg = lane >> 4;
  const int col = lane & 15;
  const int hl = lane >> 4;
  const int s16 = lane & 15;
  const int arow_l = (wave * 16 + col) * 64;
  const int asw = col & 7;

  float acc_carry = 0.f;

  for (int rep = 0; rep < NREP; ++rep) {
    int rt = blockIdx.x + rep * 260;
    if (rt >= nblk) rt -= nblk;                 // 260*5=1300 < nblk, one sub ok
    const int r0 = rt * BM;

    const float* aSrc[4];
    #pragma unroll
    for (int p = 0; p < 4; ++p) {
      int rl = p * 4 + hl;
      int rg = min(r0 + wave * 16 + rl, N - 1);
      int cu = s16 ^ (rl & 7);
      aSrc[p] = z0 + (size_t)rg * D_NLP + cu * 4;
    }

    auto stageA = [&](int t, int buf) {
      #pragma unroll
      for (int p = 0; p < 4; ++p) {
        __builtin_amdgcn_global_load_lds(
            (const __attribute__((address_space(1))) void*)(aSrc[p] + t * BK),
            (__attribute__((address_space(3))) void*)&Al[buf * 4096 + (wave * 16 + p * 4) * 64],
            16, 0, 0);
      }
    };
    auto stageB = [&](int t, int buf) {
      const unsigned short* g = w0s + (size_t)t * (D_EMB * BK) + (size_t)tid * 8;
      #pragma unroll
      for (int p = 0; p < 4; ++p) {
        __builtin_amdgcn_global_load_lds(
            (const __attribute__((address_space(1))) void*)(g + p * 256 * 8),
            (__attribute__((address_space(3))) void*)&Bl[buf * 8192 + (wave * 64 + p * 256) * 8],
            16, 0, 0);
      }
    };

    f32x4 acc[8];
    #pragma unroll
    for (int c = 0; c < 8; ++c) acc[c] = (f32x4){0.f, 0.f, 0.f, 0.f};

    stageB(0, 0);
    stageA(0, 0);
    stageA(1, 1);

    #pragma unroll
    for (int t = 0; t < NKC; ++t) {
      if (t < NKC - 1) asm volatile("s_waitcnt vmcnt(4)" ::: "memory");
      else             asm volatile("s_waitcnt vmcnt(0)" ::: "memory");
      __builtin_amdgcn_s_barrier();
      if (t + 1 < NKC) stageB(t + 1, (t + 1) & 1);
      if (t + 2 < NKC) stageA(t + 2, (t + 2) % 3);
      __builtin_amdgcn_sched_barrier(0);

      if constexpr (MODE >= 1) {
        const float* Ab = Al + (t % 3) * 4096;
        const unsigned short* Bbuf = Bl + (t & 1) * 8192;
        #pragma unroll
        for (int ks = 0; ks < 2; ++ks) {
          int u0 = ks * 8 + kg * 2;
          float4 lo = *(const float4*)&Ab[arow_l + ((u0)     ^ asw) * 4];
          float4 hi = *(const float4*)&Ab[arow_l + ((u0 + 1) ^ asw) * 4];
          if constexpr (MODE == 1) { sink4(lo); sink4(hi); }
          bf16x8 af;
          if constexpr (MODE == 2) af = pack8(lo, hi);
          #pragma unroll
          for (int c = 0; c < 8; ++c) {
            int brow = c * 16 + col;
            const unsigned short* bp = &Bbuf[(brow * 8 + ((ks * 4 + kg) ^ (brow & 7))) * 8];
            if constexpr (MODE == 1) {
              sinku4(*(const uint4*)bp);
            } else if constexpr (MODE == 2) {
              bf16x8 bfr = *(const bf16x8*)bp;
              acc[c] = __builtin_amdgcn_mfma_f32_16x16x32_bf16(af, bfr, acc[c], 0, 0, 0);
            }
          }
        }
      }
    }

    if constexpr (MODE == 2) {
      float s = 0.f;
      #pragma unroll
      for (int c = 0; c < 8; ++c)
        #pragma unroll
        for (int i = 0; i < 4; ++i) s += acc[c][i];
      acc_carry += s;
    }
  }

  if constexpr (MODE == 2) {
    dummy[(size_t)blockIdx.x * 256 + tid] = acc_carry;
  } else {
    // keep LDS arrays + staged data observed (DCE guard, rule #17)
    float x = Al[tid];
    float y = ((const float*)Bl)[tid];
    asm volatile("" :: "v"(x), "v"(y));
    if (tid == 1024) dummy[0] = x + y;   // never true; forces ptr liveness
  }
}

// ======================= PRODUCTION PATH (R11, unchanged) =======================
__global__ __launch_bounds__(256) void kc(
    const float* __restrict__ z0, const float* __restrict__ z,
    const unsigned short* __restrict__ w0s, const float* __restrict__ w1,
    const float* __restrict__ prelu_a, float* __restrict__ sv,
    float* __restrict__ ta, float* __restrict__ tb, int N) {
  extern __shared__ char smem[];
  float* Al = (float*)smem;                          // 3 x 64rows x 64f = 48KB
  unsigned short* Bl = (unsigned short*)(smem + 49152);  // 2 x 8192 = 32KB

  const int tid = threadIdx.x;
  const int lane = tid & 63;
  const int wave = tid >> 6;
  const int kg = lane >> 4;
  const int col = lane & 15;
  const int s16 = lane & 15;
  const int hl = lane >> 4;
  const int r0 = blockIdx.x * BM;
  const int myrow = r0 + wave * 16 + col;
  const int arow_g = min(myrow, N - 1);

  const float* aSrc[4];
  #pragma unroll
  for (int p = 0; p < 4; ++p) {
    int rl = p * 4 + hl;
    int rg = min(r0 + wave * 16 + rl, N - 1);
    int cu = s16 ^ (rl & 7);
    aSrc[p] = z0 + (size_t)rg * D_NLP + cu * 4;
  }

  auto stageA = [&](int t, int buf) {
    #pragma unroll
    for (int p = 0; p < 4; ++p) {
      __builtin_amdgcn_global_load_lds(
          (const __attribute__((address_space(1))) void*)(aSrc[p] + t * BK),
          (__attribute__((address_space(3))) void*)&Al[buf * 4096 + (wave * 16 + p * 4) * 64],
          16, 0, 0);
    }
  };
  auto stageB = [&](int t, int buf) {
    const unsigned short* g = w0s + (size_t)t * (D_EMB * BK) + (size_t)tid * 8;
    #pragma unroll
    for (int p = 0; p < 4; ++p) {
      __builtin_amdgcn_global_load_lds(
          (const __attribute__((address_space(1))) void*)(g + p * 256 * 8),
          (__attribute__((address_space(3))) void*)&Bl[buf * 8192 + (wave * 64 + p * 256) * 8],
          16, 0, 0);
    }
  };

  f32x4 acc[8];
  #pragma unroll
  for (int c = 0; c < 8; ++c) acc[c] = (f32x4){0.f, 0.f, 0.f, 0.f};

  stageB(0, 0);
  stageA(0, 0);
  stageA(1, 1);

  const int arow_l = (wave * 16 + col) * 64;
  const int asw = col & 7;

  #pragma unroll
  for (int t = 0; t < NKC; ++t) {
    if (t < NKC - 1) asm volatile("s_waitcnt vmcnt(4)" ::: "memory");
    else             asm volatile("s_waitcnt vmcnt(0)" ::: "memory");
    __builtin_amdgcn_s_barrier();
    if (t + 1 < NKC) stageB(t + 1, (t + 1) & 1);
    if (t + 2 < NKC) stageA(t + 2, (t + 2) % 3);
    __builtin_amdgcn_sched_barrier(0);

    const float* Ab = Al + (t % 3) * 4096;
    const unsigned short* Bbuf = Bl + (t & 1) * 8192;
    #pragma unroll
    for (int ks = 0; ks < 2; ++ks) {
      int u0 = ks * 8 + kg * 2;
      float4 lo = *(const float4*)&Ab[arow_l + ((u0)     ^ asw) * 4];
      float4 hi = *(const float4*)&Ab[arow_l + ((u0 + 1) ^ asw) * 4];
      bf16x8 af = pack8(lo, hi);
      #pragma unroll
      for (int c = 0; c < 8; ++c) {
        int brow = c * 16 + col;
        bf16x8 bfr = *(const bf16x8*)&Bbuf[(brow * 8 + ((ks * 4 + kg) ^ (brow & 7))) * 8];
        acc[c] = __builtin_amdgcn_mfma_f32_16x16x32_bf16(af, bfr, acc[c], 0, 0, 0);
      }
    }
  }

  float ap = prelu_a[0];
  float ssum[4] = {0.f, 0.f, 0.f, 0.f};
  #pragma unroll
  for (int c = 0; c < 8; ++c) {
    float wc = w1[2 * D_EMB + c * 16 + col];
    #pragma unroll
    for (int i = 0; i < 4; ++i) {
      float h = acc[c][i];
      float x = h >= 0.f ? h : ap * h;
      ssum[i] += x * wc;
    }
  }
  #pragma unroll
  for (int off = 1; off < 16; off <<= 1) {
    #pragma unroll
    for (int i = 0; i < 4; ++i) ssum[i] += __shfl_xor(ssum[i], off);
  }
  if (col == 0) {
    int rbase = r0 + wave * 16 + kg * 4;
    #pragma unroll
    for (int i = 0; i < 4; ++i) {
      int r = rbase + i;
      if (r < N) sv[r] = ssum[i];
    }
  }

  {
    const float* zp = z + (size_t)arow_g * D_EMB + kg * 32;
    const float4* wa4 = (const float4*)(w1 + kg * 32);
    const float4* wb4 = (const float4*)(w1 + D_EMB + kg * 32);
    float pa = 0.f, pb = 0.f;
    #pragma unroll
    for (int i = 0; i < 8; ++i) {
      float4 zv = ((const float4*)zp)[i];
      float4 wa = wa4[i];
      float4 wb = wb4[i];
      pa += zv.x * wa.x + zv.y * wa.y + zv.z * wa.z + zv.w * wa.w;
      pb += zv.x * wb.x + zv.y * wb.y + zv.z * wb.z + zv.w * wb.w;
    }
    pa += __shfl_xor(pa, 16); pa += __shfl_xor(pa, 32);
    pb += __shfl_xor(pb, 16); pb += __shfl_xor(pb, 32);
    if (kg == 0 && myrow < N) { ta[myrow] = pa; tb[myrow] = pb; }
  }
}

// ---- kernel D: per-edge gather + add
__global__ void kd(const int* __restrict__ ei, const int* __restrict__ mn,
                   const float* __restrict__ ta, const float* __restrict__ tb,
                   const float* __restrict__ sv, const float* __restrict__ b1,
                   float* __restrict__ out, int E) {
  int e = blockIdx.x * blockDim.x + threadIdx.x;
  if (e >= E) return;
  int i0 = ei[e], i1 = ei[E + e];
  int q = (i0 > i1 ? i0 : i1) - mn[0];
  out[e] = ta[i0] + tb[i1] + sv[q] + b1[0];
}

extern "C" void kernel_launch(void* const* d_in, const int* in_sizes, int n_in,
                              void* d_out, int out_size, void* d_ws, size_t ws_size,
                              hipStream_t stream) {
  const float* z  = (const float*)d_in[0];
  const float* z0 = (const float*)d_in[1];
  const int*   ei = (const int*)d_in[2];
  const float* w0 = (const float*)d_in[3];
  const float* pa = (const float*)d_in[4];
  const float* w1 = (const float*)d_in[5];
  const float* b1 = (const float*)d_in[6];
  float* out = (float*)d_out;
  const int N = in_sizes[0] / D_EMB;
  const int E = in_sizes[2] / 2;
  const int nblk = (N + BM - 1) / BM;

  // ws: [0,4) mn | [256,+192KB) w0s | ta[N], tb[N], sv[N] | dummy @ 2MB
  char* ws = (char*)d_ws;
  int* mn = (int*)ws;
  unsigned short* w0s = (unsigned short*)(ws + 256);
  float* ta = (float*)(ws + 256 + 196608);
  float* tb = ta + N;
  float* sv = tb + N;
  float* dummy = (float*)(ws + (2u << 20));

  hipFuncSetAttribute((const void*)kc,
                      hipFuncAttributeMaxDynamicSharedMemorySize, 81920);
  hipFuncSetAttribute((const void*)kdiag<0>,
                      hipFuncAttributeMaxDynamicSharedMemorySize, 81920);
  hipFuncSetAttribute((const void*)kdiag<1>,
                      hipFuncAttributeMaxDynamicSharedMemorySize, 81920);
  hipFuncSetAttribute((const void*)kdiag<2>,
                      hipFuncAttributeMaxDynamicSharedMemorySize, 81920);

  kw<<<(D_EMB * D_NLP / 8 + 255) / 256, 256, 0, stream>>>(w0, w0s, mn);
  km<<<256, 256, 0, stream>>>(ei, E, mn);

  // diagnostics (visible in rocprof top-5; dummy writes only)
  kdiag<0><<<nblk, 256, 81920, stream>>>(z0, w0s, dummy, N, nblk);
  kdiag<1><<<nblk, 256, 81920, stream>>>(z0, w0s, dummy, N, nblk);
  kdiag<2><<<nblk, 256, 81920, stream>>>(z0, w0s, dummy, N, nblk);

  // production
  kc<<<nblk, 256, 81920, stream>>>(z0, z, w0s, w1, pa, sv, ta, tb, N);
  kd<<<(E + 255) / 256, 256, 0, stream>>>(ei, mn, ta, tb, sv, b1, out, E);
}

// Round 13
// 152.467 us; speedup vs baseline: 6.6660x; 6.6660x over previous
//
#include <hip/hip_runtime.h>
#include <hip/hip_bf16.h>
#include <stdint.h>

#define D_EMB 128
#define D_NLP 768
#define BM 64
#define BK 64
#define NKC (D_NLP / BK)   // 12 k-chunks
#define NB 512             // persistent blocks: 2/CU x 256 CUs

typedef __attribute__((ext_vector_type(8))) short bf16x8;
typedef __attribute__((ext_vector_type(4))) float f32x4;
typedef __attribute__((ext_vector_type(8))) unsigned short u16x8;

__device__ __forceinline__ unsigned short f2bf(float f) {
  unsigned u = __builtin_bit_cast(unsigned, f);
  u += 0x7fffu + ((u >> 16) & 1u);   // RTNE (NaN-free inputs)
  return (unsigned short)(u >> 16);
}

__device__ __forceinline__ bf16x8 pack8(const float4& a, const float4& b) {
  u16x8 v;
  v[0] = __builtin_bit_cast(unsigned short, __float2bfloat16(a.x));
  v[1] = __builtin_bit_cast(unsigned short, __float2bfloat16(a.y));
  v[2] = __builtin_bit_cast(unsigned short, __float2bfloat16(a.z));
  v[3] = __builtin_bit_cast(unsigned short, __float2bfloat16(a.w));
  v[4] = __builtin_bit_cast(unsigned short, __float2bfloat16(b.x));
  v[5] = __builtin_bit_cast(unsigned short, __float2bfloat16(b.y));
  v[6] = __builtin_bit_cast(unsigned short, __float2bfloat16(b.z));
  v[7] = __builtin_bit_cast(unsigned short, __float2bfloat16(b.w));
  return __builtin_bit_cast(bf16x8, v);
}

// ---- kernel W: w0 (128x768 f32) -> bf16, pre-swizzled per 64-k chunk (B path).
__global__ void kw(const float* __restrict__ w0, unsigned short* __restrict__ w0s,
                   int* __restrict__ mn) {
  if (blockIdx.x == 0 && threadIdx.x == 0) mn[0] = 0x7fffffff;
  int t = blockIdx.x * 256 + threadIdx.x;       // 12288 units
  if (t >= (D_EMB * D_NLP) / 8) return;
  int u = t & 7, row = (t >> 3) & 127, kc = t >> 10;
  const float4* src = (const float4*)(w0 + (size_t)row * D_NLP + kc * 64 + ((u ^ (row & 7)) * 8));
  float4 v0 = src[0], v1 = src[1];
  u16x8 o;
  o[0] = f2bf(v0.x); o[1] = f2bf(v0.y); o[2] = f2bf(v0.z); o[3] = f2bf(v0.w);
  o[4] = f2bf(v1.x); o[5] = f2bf(v1.y); o[6] = f2bf(v1.z); o[7] = f2bf(v1.w);
  *(u16x8*)(w0s + (size_t)t * 8) = o;
}

// ---- kernel M: mn = min_e max(ei[0][e], ei[1][e])
__global__ void km(const int* __restrict__ ei, int E, int* __restrict__ mn) {
  int t = blockIdx.x * blockDim.x + threadIdx.x;
  int stride = gridDim.x * blockDim.x;
  int m = 0x7fffffff;
  for (int e = t; e < E; e += stride) {
    int a = ei[e], b = ei[E + e];
    int q = a > b ? a : b;
    m = q < m ? q : m;
  }
  #pragma unroll
  for (int off = 32; off; off >>= 1) {
    int o = __shfl_xor(m, off);
    m = o < m ? o : m;
  }
  if ((threadIdx.x & 63) == 0) atomicMin(mn, m);
}

// ---- kernel C: PERSISTENT blocks (kdiag-validated structure: 6-rep ablation
// ran at ~6 TB/s demand with the identical inner pipeline). Each of 512 blocks
// iterates tiles bid, bid+512, ... with the software pipeline running
// CONTINUOUSLY across tile boundaries: next tile's chunk-0/1 stages are issued
// at the current tile's t=11 barrier (target buffers provably retired), and
// the z-epilogue loads are issued BEFORE them so their use-wait leaves the
// stages in flight.
__global__ __launch_bounds__(256) void kc(
    const float* __restrict__ z0, const float* __restrict__ z,
    const unsigned short* __restrict__ w0s, const float* __restrict__ w1,
    const float* __restrict__ prelu_a, float* __restrict__ sv,
    float* __restrict__ ta, float* __restrict__ tb, int N, int NT) {
  extern __shared__ char smem[];
  float* Al = (float*)smem;                              // 3 x 64 x 64f = 48KB
  unsigned short* Bl = (unsigned short*)(smem + 49152);  // 2 x 8192 = 32KB

  const int tid = threadIdx.x;
  const int lane = tid & 63;
  const int wave = tid >> 6;
  const int kg = lane >> 4;
  const int col = lane & 15;
  const int s16 = lane & 15;
  const int hl = lane >> 4;
  const int arow_l = (wave * 16 + col) * 64;
  const int asw = col & 7;

  auto mkSrc = [&](int tile, const float* (&dst)[4]) {
    int r0 = tile * BM;
    #pragma unroll
    for (int p = 0; p < 4; ++p) {
      int rl = p * 4 + hl;
      int rg = min(r0 + wave * 16 + rl, N - 1);
      dst[p] = z0 + (size_t)rg * D_NLP + (s16 ^ (rl & 7)) * 4;
    }
  };
  auto stageA = [&](const float* const (&src)[4], int t, int buf) {
    #pragma unroll
    for (int p = 0; p < 4; ++p) {
      __builtin_amdgcn_global_load_lds(
          (const __attribute__((address_space(1))) void*)(src[p] + t * BK),
          (__attribute__((address_space(3))) void*)&Al[buf * 4096 + (wave * 16 + p * 4) * 64],
          16, 0, 0);
    }
  };
  auto stageB = [&](int t, int buf) {
    const unsigned short* g = w0s + (size_t)t * (D_EMB * BK) + (size_t)tid * 8;
    #pragma unroll
    for (int p = 0; p < 4; ++p) {
      __builtin_amdgcn_global_load_lds(
          (const __attribute__((address_space(1))) void*)(g + p * 256 * 8),
          (__attribute__((address_space(3))) void*)&Bl[buf * 8192 + (wave * 64 + p * 256) * 8],
          16, 0, 0);
    }
  };

  f32x4 acc[8];
  #pragma unroll
  for (int c = 0; c < 8; ++c) acc[c] = (f32x4){0.f, 0.f, 0.f, 0.f};

  const float ap = prelu_a[0];
  float wcf[8];
  #pragma unroll
  for (int c = 0; c < 8; ++c) wcf[c] = w1[2 * D_EMB + c * 16 + col];

  // prologue: first tile's chunks 0,1
  const float* aSrc[4];
  mkSrc(blockIdx.x, aSrc);
  stageB(0, 0);
  stageA(aSrc, 0, 0);
  stageA(aSrc, 1, 1);

  for (int tile = blockIdx.x; tile < NT; tile += NB) {
    const int r0 = tile * BM;
    const int myrow = r0 + wave * 16 + col;
    const int arow_g = min(myrow, N - 1);
    const bool hasNext = tile + NB < NT;
    const float* aSrcN[4];
    mkSrc(tile + NB, aSrcN);          // clamped -> safe even when !hasNext

    float4 zr[8];

    #pragma unroll
    for (int t = 0; t < NKC; ++t) {
      if (t < NKC - 1) asm volatile("s_waitcnt vmcnt(4)" ::: "memory");
      else             asm volatile("s_waitcnt vmcnt(0)" ::: "memory");
      __builtin_amdgcn_s_barrier();
      if (t == NKC - 1) {
        // z-epilogue loads FIRST (so their use-wait leaves next stages flying)
        const float4* zp = (const float4*)(z + (size_t)arow_g * D_EMB + kg * 32);
        #pragma unroll
        for (int i = 0; i < 8; ++i) zr[i] = zp[i];
        if (hasNext) {                 // next tile's chunks 0,1 into bufs 0/0,1
          stageB(0, 0);
          stageA(aSrcN, 0, 0);
          stageA(aSrcN, 1, 1);
        }
      } else {
        stageB(t + 1, (t + 1) & 1);
        if (t + 2 < NKC) stageA(aSrc, t + 2, (t + 2) % 3);
      }
      __builtin_amdgcn_sched_barrier(0);

      const float* Ab = Al + (t % 3) * 4096;
      const unsigned short* Bbuf = Bl + (t & 1) * 8192;
      #pragma unroll
      for (int ks = 0; ks < 2; ++ks) {
        int u0 = ks * 8 + kg * 2;
        float4 lo = *(const float4*)&Ab[arow_l + ((u0)     ^ asw) * 4];
        float4 hi = *(const float4*)&Ab[arow_l + ((u0 + 1) ^ asw) * 4];
        bf16x8 af = pack8(lo, hi);
        #pragma unroll
        for (int c = 0; c < 8; ++c) {
          int brow = c * 16 + col;
          bf16x8 bfr = *(const bf16x8*)&Bbuf[(brow * 8 + ((ks * 4 + kg) ^ (brow & 7))) * 8];
          acc[c] = __builtin_amdgcn_mfma_f32_16x16x32_bf16(af, bfr, acc[c], 0, 0, 0);
        }
      }
    }
    #pragma unroll
    for (int p = 0; p < 4; ++p) aSrc[p] = aSrcN[p];

    // epilogue 1 (VALU-only first): prelu + * w1c, 16-col reduce from acc
    float ssum[4] = {0.f, 0.f, 0.f, 0.f};
    #pragma unroll
    for (int c = 0; c < 8; ++c) {
      #pragma unroll
      for (int i = 0; i < 4; ++i) {
        float h = acc[c][i];
        float x = h >= 0.f ? h : ap * h;
        ssum[i] += x * wcf[c];
      }
    }
    #pragma unroll
    for (int off = 1; off < 16; off <<= 1) {
      #pragma unroll
      for (int i = 0; i < 4; ++i) ssum[i] += __shfl_xor(ssum[i], off);
    }
    if (col == 0) {
      int rbase = r0 + wave * 16 + kg * 4;   // C/D row = (lane>>4)*4 + i
      #pragma unroll
      for (int i = 0; i < 4; ++i) {
        int r = rbase + i;
        if (r < N) sv[r] = ssum[i];
      }
    }
    #pragma unroll
    for (int c = 0; c < 8; ++c) acc[c] = (f32x4){0.f, 0.f, 0.f, 0.f};

    // epilogue 2 (fused kt): uses preloaded zr (wait leaves stages in flight)
    {
      const float4* wa4 = (const float4*)(w1 + kg * 32);
      const float4* wb4 = (const float4*)(w1 + D_EMB + kg * 32);
      float pa = 0.f, pb = 0.f;
      #pragma unroll
      for (int i = 0; i < 8; ++i) {
        float4 zv = zr[i];
        float4 wa = wa4[i];
        float4 wb = wb4[i];
        pa += zv.x * wa.x + zv.y * wa.y + zv.z * wa.z + zv.w * wa.w;
        pb += zv.x * wb.x + zv.y * wb.y + zv.z * wb.z + zv.w * wb.w;
      }
      pa += __shfl_xor(pa, 16); pa += __shfl_xor(pa, 32);
      pb += __shfl_xor(pb, 16); pb += __shfl_xor(pb, 32);
      if (kg == 0 && myrow < N) { ta[myrow] = pa; tb[myrow] = pb; }
    }
  }
}

// ---- kernel D: per-edge gather + add
__global__ void kd(const int* __restrict__ ei, const int* __restrict__ mn,
                   const float* __restrict__ ta, const float* __restrict__ tb,
                   const float* __restrict__ sv, const float* __restrict__ b1,
                   float* __restrict__ out, int E) {
  int e = blockIdx.x * blockDim.x + threadIdx.x;
  if (e >= E) return;
  int i0 = ei[e], i1 = ei[E + e];
  int q = (i0 > i1 ? i0 : i1) - mn[0];
  out[e] = ta[i0] + tb[i1] + sv[q] + b1[0];
}

extern "C" void kernel_launch(void* const* d_in, const int* in_sizes, int n_in,
                              void* d_out, int out_size, void* d_ws, size_t ws_size,
                              hipStream_t stream) {
  const float* z  = (const float*)d_in[0];
  const float* z0 = (const float*)d_in[1];
  const int*   ei = (const int*)d_in[2];
  const float* w0 = (const float*)d_in[3];
  const float* pa = (const float*)d_in[4];
  const float* w1 = (const float*)d_in[5];
  const float* b1 = (const float*)d_in[6];
  float* out = (float*)d_out;
  const int N = in_sizes[0] / D_EMB;
  const int E = in_sizes[2] / 2;
  const int NT = (N + BM - 1) / BM;

  // ws: [0,4) mn | [256,+192KB) w0s bf16 pre-swizzled | ta[N], tb[N], sv[N]
  char* ws = (char*)d_ws;
  int* mn = (int*)ws;
  unsigned short* w0s = (unsigned short*)(ws + 256);
  float* ta = (float*)(ws + 256 + 196608);
  float* tb = ta + N;
  float* sv = tb + N;

  hipFuncSetAttribute((const void*)kc,
                      hipFuncAttributeMaxDynamicSharedMemorySize, 81920);

  kw<<<(D_EMB * D_NLP / 8 + 255) / 256, 256, 0, stream>>>(w0, w0s, mn);
  km<<<256, 256, 0, stream>>>(ei, E, mn);
  kc<<<(NT < NB ? NT : NB), 256, 81920, stream>>>(z0, z, w0s, w1, pa, sv, ta, tb, N, NT);
  kd<<<(E + 255) / 256, 256, 0, stream>>>(ei, mn, ta, tb, sv, b1, out, E);
}